// Round 1
// baseline (345.840 us; speedup 1.0000x reference)
//
#include <hip/hip_runtime.h>

#define S_ 8192
#define H_ 8
#define D_ 64
#define M_ 64
#define C_ 65            // D + 1 (v concat ones)
#define BH_ 32           // B*H = 4*8

// x' = x * NORMALIZER * log2(e); h' = 0.5*ln2*||x'||^2 (= log2e * 0.5*||x||^2)
// phi = exp2(x'.p - h' - 3)   (the -3 folds the 1/sqrt(M)=1/8)
constexpr float XS_ = 0.35355339059327373f * 1.4426950408889634f;
constexpr float HS_ = 0.34657359027997264f;   // 0.5 * ln2
constexpr float EPS_ = 1e-6f;

__device__ __forceinline__ float fexp2(float x) { return __builtin_amdgcn_exp2f(x); }

// ---------------------------------------------------------------------------
// Phase K: per (bh, chunk) block, accumulate partial buf1[64][65] over a chunk
// of k-rows. Wave-per-row: lane m holds proj row m (regs) + acc row m (regs).
// ---------------------------------------------------------------------------
__global__ void __launch_bounds__(256)
fa_phase_k(const float* __restrict__ ks, const float* __restrict__ vs,
           const float* __restrict__ proj, float* __restrict__ partial, int nch)
{
    const int chunk = blockIdx.x;
    const int bh    = blockIdx.y;
    const int b = bh >> 3, h = bh & 7;
    const int rows = S_ / nch;            // multiple of 16
    const int s0   = chunk * rows;
    const int tid  = threadIdx.x;
    const int wid  = tid >> 6, lane = tid & 63;
    const int rl   = lane >> 4;           // which of 4 rows this lane stages
    const int d0   = (lane & 15) << 2;    // float4 offset within row

    __shared__ float xbuf[4][4][64];      // [wave][row][d]
    __shared__ float vbuf[4][4][64];
    __shared__ float red[M_ * C_];

    // proj row `lane` into registers
    float pm[D_];
#pragma unroll
    for (int i = 0; i < 16; ++i) {
        float4 p = reinterpret_cast<const float4*>(proj)[lane * 16 + i];
        pm[4*i+0] = p.x; pm[4*i+1] = p.y; pm[4*i+2] = p.z; pm[4*i+3] = p.w;
    }
    float acc[C_];
#pragma unroll
    for (int c = 0; c < C_; ++c) acc[c] = 0.f;

    const size_t rowstride = (size_t)H_ * D_;
    const float* kbase = ks + ((size_t)b * S_ * H_ + h) * D_ + d0;
    const float* vbase = vs + ((size_t)b * S_ * H_ + h) * D_ + d0;

    int s = s0 + (wid << 2) + rl;
    float4 kx = *reinterpret_cast<const float4*>(kbase + (size_t)s * rowstride);
    float4 vx = *reinterpret_cast<const float4*>(vbase + (size_t)s * rowstride);

    for (int it = 0; it < rows; it += 16) {
        kx.x *= XS_; kx.y *= XS_; kx.z *= XS_; kx.w *= XS_;
        *reinterpret_cast<float4*>(&xbuf[wid][rl][d0]) = kx;
        *reinterpret_cast<float4*>(&vbuf[wid][rl][d0]) = vx;
        float sq = kx.x*kx.x + kx.y*kx.y + kx.z*kx.z + kx.w*kx.w;
        sq += __shfl_xor(sq, 1);
        sq += __shfl_xor(sq, 2);
        sq += __shfl_xor(sq, 4);
        sq += __shfl_xor(sq, 8);          // 16-lane groups: row sumsq
        float hh = sq * HS_ + 3.0f;       // h' + 3

        // prefetch next iteration's rows
        int itn = it + 16;
        if (itn < rows) {
            int sn = s0 + itn + (wid << 2) + rl;
            kx = *reinterpret_cast<const float4*>(kbase + (size_t)sn * rowstride);
            vx = *reinterpret_cast<const float4*>(vbase + (size_t)sn * rowstride);
        }

#pragma unroll
        for (int r = 0; r < 4; ++r) {
            float hr = __shfl(hh, r << 4);
            float xp0 = 0.f, xp1 = 0.f, xp2 = 0.f, xp3 = 0.f;
#pragma unroll
            for (int d4 = 0; d4 < 16; ++d4) {   // broadcast LDS reads
                float4 xv = *reinterpret_cast<const float4*>(&xbuf[wid][r][d4 << 2]);
                xp0 += xv.x * pm[4*d4+0];
                xp1 += xv.y * pm[4*d4+1];
                xp2 += xv.z * pm[4*d4+2];
                xp3 += xv.w * pm[4*d4+3];
            }
            float e = fexp2((xp0 + xp1) + (xp2 + xp3) - hr);
#pragma unroll
            for (int c4 = 0; c4 < 16; ++c4) {
                float4 vv = *reinterpret_cast<const float4*>(&vbuf[wid][r][c4 << 2]);
                acc[4*c4+0] += e * vv.x;
                acc[4*c4+1] += e * vv.y;
                acc[4*c4+2] += e * vv.z;
                acc[4*c4+3] += e * vv.w;
            }
            acc[64] += e;                  // ones column
        }
    }

    // cross-wave reduce into LDS (deterministic), then write partial
    for (int i = tid; i < M_ * C_; i += 256) red[i] = 0.f;
    __syncthreads();
    for (int w = 0; w < 4; ++w) {
        if (wid == w) {
#pragma unroll
            for (int c = 0; c < C_; ++c) red[lane * C_ + c] += acc[c];
        }
        __syncthreads();
    }
    float* dst = partial + ((size_t)bh * nch + chunk) * (M_ * C_);
    for (int i = tid; i < M_ * C_; i += 256) dst[i] = red[i];
}

// ---------------------------------------------------------------------------
// Reduce partials -> buf1[bh][64][65]
// ---------------------------------------------------------------------------
__global__ void __launch_bounds__(256)
fa_reduce(const float* __restrict__ partial, float* __restrict__ buf1, int nch)
{
    const int bh = blockIdx.x;
    for (int i = threadIdx.x; i < M_ * C_; i += 256) {
        float sum = 0.f;
        for (int ch = 0; ch < nch; ++ch)
            sum += partial[((size_t)bh * nch + ch) * (M_ * C_) + i];
        buf1[(size_t)bh * (M_ * C_) + i] = sum;
    }
}

// ---------------------------------------------------------------------------
// Phase Q: thread-per-row. q row in regs; proj + buf1 in LDS (broadcast reads).
// out = (qp . buf1[:, :64]) / max(qp . buf1[:,64], EPS)
// ---------------------------------------------------------------------------
__global__ void __launch_bounds__(256)
fa_phase_q(const float* __restrict__ qs, const float* __restrict__ proj,
           const float* __restrict__ buf1, float* __restrict__ out)
{
    const int chunk = blockIdx.x;     // 32 chunks of 256 rows
    const int bh    = blockIdx.y;
    const int b = bh >> 3, h = bh & 7;
    const int tid = threadIdx.x;
    const int s   = chunk * 256 + tid;

    __shared__ float pl[M_ * D_];     // proj [m][d]
    __shared__ float b1[M_][68];      // buf1 rows padded to 68 (16B-aligned rows)

    for (int i = tid; i < M_ * D_; i += 256) pl[i] = proj[i];
    const float* b1src = buf1 + (size_t)bh * (M_ * C_);
    for (int i = tid; i < M_ * 68; i += 256) {
        int m = i / 68, c = i - m * 68;
        b1[m][c] = (c < C_) ? b1src[m * C_ + c] : 0.f;
    }
    __syncthreads();

    const size_t base = ((size_t)b * S_ * H_ + (size_t)s * H_ + h) * D_;

    float x[D_];
    float hh = 0.f;
#pragma unroll
    for (int i = 0; i < 16; ++i) {
        float4 q4 = *reinterpret_cast<const float4*>(qs + base + 4 * i);
        x[4*i+0] = q4.x * XS_; x[4*i+1] = q4.y * XS_;
        x[4*i+2] = q4.z * XS_; x[4*i+3] = q4.w * XS_;
        hh += x[4*i+0]*x[4*i+0] + x[4*i+1]*x[4*i+1]
            + x[4*i+2]*x[4*i+2] + x[4*i+3]*x[4*i+3];
    }
    hh = hh * HS_ + 3.0f;

    float acc[68];
#pragma unroll
    for (int c = 0; c < 68; ++c) acc[c] = 0.f;

#pragma unroll 2
    for (int m = 0; m < M_; ++m) {
        float xp0 = 0.f, xp1 = 0.f, xp2 = 0.f, xp3 = 0.f;
#pragma unroll
        for (int d4 = 0; d4 < 16; ++d4) {   // uniform-address broadcast
            float4 p = *reinterpret_cast<const float4*>(&pl[m * D_ + 4 * d4]);
            xp0 += p.x * x[4*d4+0];
            xp1 += p.y * x[4*d4+1];
            xp2 += p.z * x[4*d4+2];
            xp3 += p.w * x[4*d4+3];
        }
        float e = fexp2((xp0 + xp1) + (xp2 + xp3) - hh);
#pragma unroll
        for (int c4 = 0; c4 < 17; ++c4) {
            float4 bb = *reinterpret_cast<const float4*>(&b1[m][4 * c4]);
            acc[4*c4+0] += e * bb.x;
            acc[4*c4+1] += e * bb.y;
            acc[4*c4+2] += e * bb.z;
            acc[4*c4+3] += e * bb.w;
        }
    }

    float den = acc[64];
    den = den < EPS_ ? EPS_ : den;
    float rd = 1.0f / den;
#pragma unroll
    for (int i = 0; i < 16; ++i) {
        float4 o;
        o.x = acc[4*i+0] * rd; o.y = acc[4*i+1] * rd;
        o.z = acc[4*i+2] * rd; o.w = acc[4*i+3] * rd;
        *reinterpret_cast<float4*>(out + base + 4 * i) = o;
    }
}

extern "C" void kernel_launch(void* const* d_in, const int* in_sizes, int n_in,
                              void* d_out, int out_size, void* d_ws, size_t ws_size,
                              hipStream_t stream)
{
    const float* qs   = (const float*)d_in[0];
    const float* ks   = (const float*)d_in[1];
    const float* vs   = (const float*)d_in[2];
    const float* proj = (const float*)d_in[3];
    float* out = (float*)d_out;

    int nch = 32;
    while (nch > 1 &&
           (size_t)BH_ * (M_ * C_) * (size_t)(nch + 1) * sizeof(float) > ws_size)
        nch >>= 1;

    float* buf1    = (float*)d_ws;                 // BH * 64*65
    float* partial = buf1 + (size_t)BH_ * (M_ * C_);

    fa_phase_k<<<dim3(nch, BH_), 256, 0, stream>>>(ks, vs, proj, partial, nch);
    fa_reduce<<<dim3(BH_), 256, 0, stream>>>(partial, buf1, nch);
    fa_phase_q<<<dim3(32, BH_), 256, 0, stream>>>(qs, proj, buf1, out);
}

// Round 2
// 303.376 us; speedup vs baseline: 1.1400x; 1.1400x over previous
//
#include <hip/hip_runtime.h>

#define S_ 8192
#define H_ 8
#define D_ 64
#define M_ 64
#define C_ 65            // D + 1 (v concat ones)
#define CP_ 68           // padded buf1 row (16B-aligned float4 rows)
#define BH_ 32           // B*H = 4*8

// x' = x * NORMALIZER * log2(e); h' = 0.5*ln2*||x'||^2
// phi = exp2(x'.p - h' - 3)   (the -3 folds the 1/sqrt(M)=1/8)
constexpr float XS_ = 0.35355339059327373f * 1.4426950408889634f;
constexpr float HS_ = 0.34657359027997264f;   // 0.5 * ln2
constexpr float EPS_ = 1e-6f;

__device__ __forceinline__ float fexp2(float x) { return __builtin_amdgcn_exp2f(x); }

// ---------------------------------------------------------------------------
// Phase K: per (bh, chunk) block, accumulate partial buf1[64][65] over a chunk
// of k-rows. Wave-per-row: lane m holds proj row m (regs) + acc row m (regs).
// k rows staged in LDS (needed for the per-row sumsq h); v rows read via
// wave-uniform scalar loads (SGPR operand in the fmac -> no LDS broadcast).
// ---------------------------------------------------------------------------
__global__ void __launch_bounds__(256)
fa_phase_k(const float* __restrict__ ks, const float* __restrict__ vs,
           const float* __restrict__ proj, float* __restrict__ partial, int nch)
{
    const int chunk = blockIdx.x;
    const int bh    = blockIdx.y;
    const int b = bh >> 3, h = bh & 7;
    const int rows = S_ / nch;            // multiple of 16
    const int s0   = chunk * rows;
    const int tid  = threadIdx.x;
    const int wid  = tid >> 6, lane = tid & 63;
    const int rl   = lane >> 4;           // which of 4 rows this lane stages
    const int d0   = (lane & 15) << 2;    // float4 offset within row

    __shared__ float xbuf[4][4][64];      // [wave][row][d]
    __shared__ float red[M_ * C_];

    // proj row `lane` into registers
    float pm[D_];
#pragma unroll
    for (int i = 0; i < 16; ++i) {
        float4 p = reinterpret_cast<const float4*>(proj)[lane * 16 + i];
        pm[4*i+0] = p.x; pm[4*i+1] = p.y; pm[4*i+2] = p.z; pm[4*i+3] = p.w;
    }
    float acc[C_];
#pragma unroll
    for (int c = 0; c < C_; ++c) acc[c] = 0.f;

    const size_t rowstride = (size_t)H_ * D_;
    const float* kbase = ks + ((size_t)b * S_ * H_ + h) * D_ + d0;
    const float* vbase = vs + ((size_t)b * S_ * H_ + h) * D_;   // no lane offset

    int s = s0 + (wid << 2) + rl;
    float4 kx = *reinterpret_cast<const float4*>(kbase + (size_t)s * rowstride);

    for (int it = 0; it < rows; it += 16) {
        kx.x *= XS_; kx.y *= XS_; kx.z *= XS_; kx.w *= XS_;
        *reinterpret_cast<float4*>(&xbuf[wid][rl][d0]) = kx;
        float sq = kx.x*kx.x + kx.y*kx.y + kx.z*kx.z + kx.w*kx.w;
        sq += __shfl_xor(sq, 1);
        sq += __shfl_xor(sq, 2);
        sq += __shfl_xor(sq, 4);
        sq += __shfl_xor(sq, 8);          // 16-lane groups: row sumsq
        float hh = sq * HS_ + 3.0f;       // h' + 3

        // prefetch next iteration's k rows
        int itn = it + 16;
        if (itn < rows) {
            int sn = s0 + itn + (wid << 2) + rl;
            kx = *reinterpret_cast<const float4*>(kbase + (size_t)sn * rowstride);
        }

#pragma unroll
        for (int r = 0; r < 4; ++r) {
            float hr = __shfl(hh, r << 4);
            float xp0 = 0.f, xp1 = 0.f, xp2 = 0.f, xp3 = 0.f;
#pragma unroll
            for (int d4 = 0; d4 < 16; ++d4) {   // broadcast LDS reads (k row)
                float4 xv = *reinterpret_cast<const float4*>(&xbuf[wid][r][d4 << 2]);
                xp0 += xv.x * pm[4*d4+0];
                xp1 += xv.y * pm[4*d4+1];
                xp2 += xv.z * pm[4*d4+2];
                xp3 += xv.w * pm[4*d4+3];
            }
            float e = fexp2((xp0 + xp1) + (xp2 + xp3) - hr);

            // v row: wave-uniform scalar loads (SGPR-resident), fmac s,v
            int srow = __builtin_amdgcn_readfirstlane(s0 + it + (wid << 2) + r);
            const float4* __restrict__ vrow =
                reinterpret_cast<const float4*>(vbase + (size_t)srow * rowstride);
#pragma unroll
            for (int c4 = 0; c4 < 16; ++c4) {
                float4 vv = vrow[c4];
                acc[4*c4+0] += e * vv.x;
                acc[4*c4+1] += e * vv.y;
                acc[4*c4+2] += e * vv.z;
                acc[4*c4+3] += e * vv.w;
            }
            acc[64] += e;                  // ones column
        }
    }

    // cross-wave reduce into LDS (deterministic), then write partial
    for (int i = tid; i < M_ * C_; i += 256) red[i] = 0.f;
    __syncthreads();
    for (int w = 0; w < 4; ++w) {
        if (wid == w) {
#pragma unroll
            for (int c = 0; c < C_; ++c) red[lane * C_ + c] += acc[c];
        }
        __syncthreads();
    }
    float* dst = partial + ((size_t)bh * nch + chunk) * (M_ * C_);
    for (int i = tid; i < M_ * C_; i += 256) dst[i] = red[i];
}

// ---------------------------------------------------------------------------
// Reduce partials -> buf1[bh][64][CP_] (padded, pads zeroed).
// One output element per thread; 4 independent accumulators to keep loads
// in flight (the old 32-block rolled loop was a 132 us latency chain).
// ---------------------------------------------------------------------------
__global__ void __launch_bounds__(256)
fa_reduce(const float* __restrict__ partial, float* __restrict__ buf1, int nch)
{
    int e = blockIdx.x * 256 + threadIdx.x;          // over BH * M * CP_
    if (e >= BH_ * M_ * CP_) return;
    int bh  = e / (M_ * CP_);
    int rem = e - bh * (M_ * CP_);
    int m = rem / CP_, c = rem - m * CP_;
    float sum = 0.f;
    if (c < C_) {
        const float* src = partial + (size_t)bh * nch * (M_ * C_) + m * C_ + c;
        float s0 = 0.f, s1 = 0.f, s2 = 0.f, s3 = 0.f;
        int ch = 0;
        for (; ch + 4 <= nch; ch += 4) {
            s0 += src[(size_t)(ch+0) * (M_ * C_)];
            s1 += src[(size_t)(ch+1) * (M_ * C_)];
            s2 += src[(size_t)(ch+2) * (M_ * C_)];
            s3 += src[(size_t)(ch+3) * (M_ * C_)];
        }
        for (; ch < nch; ++ch) s0 += src[(size_t)ch * (M_ * C_)];
        sum = (s0 + s1) + (s2 + s3);
    }
    buf1[(size_t)bh * (M_ * CP_) + m * CP_ + c] = sum;
}

// ---------------------------------------------------------------------------
// Phase Q: thread-per-row. q row in regs; proj in LDS (broadcast reads);
// buf1 rows via wave-uniform scalar loads (SGPR operands) - splits the two
// operand streams across the LDS and SMEM pipes.
// ---------------------------------------------------------------------------
__global__ void __launch_bounds__(256)
fa_phase_q(const float* __restrict__ qs, const float* __restrict__ proj,
           const float* __restrict__ buf1, float* __restrict__ out)
{
    const int chunk = blockIdx.x;     // 32 chunks of 256 rows
    const int bh    = blockIdx.y;
    const int b = bh >> 3, h = bh & 7;
    const int tid = threadIdx.x;
    const int s   = chunk * 256 + tid;

    __shared__ float pl[M_ * D_];     // proj [m][d]
    for (int i = tid; i < M_ * D_; i += 256) pl[i] = proj[i];
    __syncthreads();

    const float4* __restrict__ b1r =
        reinterpret_cast<const float4*>(buf1 + (size_t)bh * (M_ * CP_));

    const size_t base = ((size_t)b * S_ * H_ + (size_t)s * H_ + h) * D_;

    float x[D_];
    float hh = 0.f;
#pragma unroll
    for (int i = 0; i < 16; ++i) {
        float4 q4 = *reinterpret_cast<const float4*>(qs + base + 4 * i);
        x[4*i+0] = q4.x * XS_; x[4*i+1] = q4.y * XS_;
        x[4*i+2] = q4.z * XS_; x[4*i+3] = q4.w * XS_;
        hh += x[4*i+0]*x[4*i+0] + x[4*i+1]*x[4*i+1]
            + x[4*i+2]*x[4*i+2] + x[4*i+3]*x[4*i+3];
    }
    hh = hh * HS_ + 3.0f;

    float acc[CP_];
#pragma unroll
    for (int c = 0; c < CP_; ++c) acc[c] = 0.f;

#pragma unroll 2
    for (int m = 0; m < M_; ++m) {
        float xp0 = 0.f, xp1 = 0.f, xp2 = 0.f, xp3 = 0.f;
#pragma unroll
        for (int d4 = 0; d4 < 16; ++d4) {   // uniform-address LDS broadcast
            float4 p = *reinterpret_cast<const float4*>(&pl[m * D_ + 4 * d4]);
            xp0 += p.x * x[4*d4+0];
            xp1 += p.y * x[4*d4+1];
            xp2 += p.z * x[4*d4+2];
            xp3 += p.w * x[4*d4+3];
        }
        float e = fexp2((xp0 + xp1) + (xp2 + xp3) - hh);

        const float4* __restrict__ row = b1r + m * (CP_ / 4);
#pragma unroll
        for (int c4 = 0; c4 < CP_ / 4; ++c4) {  // uniform scalar loads
            float4 bb = row[c4];
            acc[4*c4+0] += e * bb.x;
            acc[4*c4+1] += e * bb.y;
            acc[4*c4+2] += e * bb.z;
            acc[4*c4+3] += e * bb.w;
        }
    }

    float den = acc[64];
    den = den < EPS_ ? EPS_ : den;
    float rd = 1.0f / den;
#pragma unroll
    for (int i = 0; i < 16; ++i) {
        float4 o;
        o.x = acc[4*i+0] * rd; o.y = acc[4*i+1] * rd;
        o.z = acc[4*i+2] * rd; o.w = acc[4*i+3] * rd;
        *reinterpret_cast<float4*>(out + base + 4 * i) = o;
    }
}

extern "C" void kernel_launch(void* const* d_in, const int* in_sizes, int n_in,
                              void* d_out, int out_size, void* d_ws, size_t ws_size,
                              hipStream_t stream)
{
    const float* qs   = (const float*)d_in[0];
    const float* ks   = (const float*)d_in[1];
    const float* vs   = (const float*)d_in[2];
    const float* proj = (const float*)d_in[3];
    float* out = (float*)d_out;

    int nch = 32;
    while (nch > 1 &&
           (size_t)BH_ * ((size_t)M_ * CP_ + (size_t)(M_ * C_) * nch) * sizeof(float) > ws_size)
        nch >>= 1;

    float* buf1    = (float*)d_ws;                 // BH * 64*68 (padded)
    float* partial = buf1 + (size_t)BH_ * (M_ * CP_);

    fa_phase_k<<<dim3(nch, BH_), 256, 0, stream>>>(ks, vs, proj, partial, nch);
    int nred = (BH_ * M_ * CP_ + 255) / 256;       // 544 blocks
    fa_reduce<<<dim3(nred), 256, 0, stream>>>(partial, buf1, nch);
    fa_phase_q<<<dim3(32, BH_), 256, 0, stream>>>(qs, proj, buf1, out);
}

// Round 3
// 72.828 us; speedup vs baseline: 4.7487x; 4.1656x over previous
//
#include <hip/hip_runtime.h>

#define S_ 8192
#define H_ 8
#define D_ 64
#define M_ 64
#define BH_ 32
#define CPK_ 80          // buf1/partial row stride (c 0..79, den at c=64)
#define NCHK 16
#define NCHQ 16
#define TILE 64
#define KTILES (S_ / NCHK / TILE)   // 8
#define QTILES (S_ / NCHQ / TILE)   // 8

typedef short bf16x8 __attribute__((ext_vector_type(8)));
typedef float f32x4 __attribute__((ext_vector_type(4)));

constexpr float XS_ = 0.35355339059327373f * 1.4426950408889634f; // D^-1/4 * log2(e)
constexpr float HS_ = 0.34657359027997264f;                        // ln2/2
constexpr float EPS_ = 1e-6f;

__device__ __forceinline__ unsigned short f2bf(float f) {
    unsigned int u = __float_as_uint(f);
    u += 0x7FFFu + ((u >> 16) & 1u);          // RNE
    return (unsigned short)(u >> 16);
}
__device__ __forceinline__ float fexp2(float x) { return __builtin_amdgcn_exp2f(x); }

#define MFMA(a, b, c) __builtin_amdgcn_mfma_f32_16x16x32_bf16((a), (b), (c), 0, 0, 0)
#define SWZ(byteoff, row) ((byteoff) ^ (((row) & 7) << 4))

// ---------------------------------------------------------------------------
// Phase K: per (chunk, bh) block. 4 waves; wave owns a 16-row strip for the
// P pass and the m-tile (wid) for buf1 accumulation (no cross-wave reduce).
//   P[row][m] = mfma(Kscaled, projT) ; e = exp2(P - h)
//   buf1[m][c] += mfma(E_T, [V,1])   via LDS-transposed eT[m][row], vT[c][row]
// ---------------------------------------------------------------------------
__global__ void __launch_bounds__(256)
fa_k(const float* __restrict__ ks, const float* __restrict__ vs,
     const float* __restrict__ proj, float* __restrict__ partial)
{
    const int chunk = blockIdx.x;
    const int bh    = blockIdx.y;
    const int b = bh >> 3, h = bh & 7;
    const int tid = threadIdx.x, wid = tid >> 6, lane = tid & 63;
    const int l15 = lane & 15, g = lane >> 4;

    __shared__ __align__(16) char eTb[2][M_ * TILE * 2];   // [m][row] bf16, swz by m
    __shared__ __align__(16) char vTb[2][D_ * TILE * 2];   // [c][row] bf16, swz by c

    const int rows = S_ / NCHK;
    const int s0 = chunk * rows;
    const size_t rs = (size_t)H_ * D_;
    const float* kb = ks + ((size_t)b * S_ * H_ + h) * D_;
    const float* vb = vs + ((size_t)b * S_ * H_ + h) * D_;

    // proj B-fragments: B[k=d][n=m]: lane: m = mt*16+l15, d = g*8+j (+32*kk)
    bf16x8 pf[4][2];
#pragma unroll
    for (int mt = 0; mt < 4; ++mt)
#pragma unroll
        for (int kk = 0; kk < 2; ++kk) {
            const float* p = proj + (mt * 16 + l15) * D_ + kk * 32 + g * 8;
            float4 a = *(const float4*)p, c = *(const float4*)(p + 4);
            bf16x8 f;
            f[0] = (short)f2bf(a.x); f[1] = (short)f2bf(a.y);
            f[2] = (short)f2bf(a.z); f[3] = (short)f2bf(a.w);
            f[4] = (short)f2bf(c.x); f[5] = (short)f2bf(c.y);
            f[6] = (short)f2bf(c.z); f[7] = (short)f2bf(c.w);
            pf[mt][kk] = f;
        }

    // ones-column B-frag (c-tile 4): B[k][c]=1 iff c==64  (lane l15==0)
    bf16x8 onef = {0, 0, 0, 0, 0, 0, 0, 0};
    if (l15 == 0) {
#pragma unroll
        for (int j = 0; j < 8; ++j) onef[j] = (short)0x3F80;
    }

    f32x4 acc[5];
#pragma unroll
    for (int ci = 0; ci < 5; ++ci) acc[ci] = (f32x4){0.f, 0.f, 0.f, 0.f};

    auto loadT = [&](int t, float4* kp, float* vp) {
        int sb = s0 + t * TILE;
        const float* krow = kb + (size_t)(sb + wid * 16 + l15) * rs;
        kp[0] = *(const float4*)(krow + g * 8);
        kp[1] = *(const float4*)(krow + g * 8 + 4);
        kp[2] = *(const float4*)(krow + 32 + g * 8);
        kp[3] = *(const float4*)(krow + 32 + g * 8 + 4);
        const float* vcol = vb + lane;
        int rb = sb + wid * 16;
#pragma unroll
        for (int r = 0; r < 16; ++r)
            vp[r] = vcol[(size_t)(rb + r) * rs];
    };

    auto body = [&](int t, int p, const float4* kc, const float* vc,
                    float4* kn, float* vn) {
        if (t + 1 < KTILES) loadT(t + 1, kn, vn);

        // scale + h for row (wid*16 + l15)
        float kx[16];
#pragma unroll
        for (int i = 0; i < 4; ++i) {
            kx[4 * i + 0] = kc[i].x * XS_; kx[4 * i + 1] = kc[i].y * XS_;
            kx[4 * i + 2] = kc[i].z * XS_; kx[4 * i + 3] = kc[i].w * XS_;
        }
        float sq = 0.f;
#pragma unroll
        for (int j = 0; j < 16; ++j) sq += kx[j] * kx[j];
        sq += __shfl_xor(sq, 16);
        sq += __shfl_xor(sq, 32);
        float hrow = sq * HS_ + 3.0f;

        bf16x8 a1[2];
#pragma unroll
        for (int j = 0; j < 8; ++j) {
            a1[0][j] = (short)f2bf(kx[j]);
            a1[1][j] = (short)f2bf(kx[8 + j]);
        }

        f32x4 pa[4];
#pragma unroll
        for (int mt = 0; mt < 4; ++mt) {
            pa[mt] = (f32x4){0.f, 0.f, 0.f, 0.f};
            pa[mt] = MFMA(a1[0], pf[mt][0], pa[mt]);
            pa[mt] = MFMA(a1[1], pf[mt][1], pa[mt]);
        }

        float hr[4];
#pragma unroll
        for (int r = 0; r < 4; ++r) hr[r] = __shfl(hrow, 4 * g + r);

        char* etp = eTb[p];
        char* vtp = vTb[p];
#pragma unroll
        for (int mt = 0; mt < 4; ++mt) {
            unsigned long long pk = 0;
#pragma unroll
            for (int r = 0; r < 4; ++r) {
                float e = fexp2(pa[mt][r] - hr[r]);
                pk |= (unsigned long long)f2bf(e) << (16 * r);
            }
            int m = mt * 16 + l15;
            *(unsigned long long*)(etp + SWZ(m * 128 + 32 * wid + 8 * g, m)) = pk;
        }
        {
            int c = lane;
            bf16x8 w0, w1;
#pragma unroll
            for (int j = 0; j < 8; ++j) {
                w0[j] = (short)f2bf(vc[j]);
                w1[j] = (short)f2bf(vc[8 + j]);
            }
            *(bf16x8*)(vtp + SWZ(c * 128 + 32 * wid, c)) = w0;
            *(bf16x8*)(vtp + SWZ(c * 128 + 32 * wid + 16, c)) = w1;
        }
        __syncthreads();

        bf16x8 a2[2];
        {
            int m = wid * 16 + l15;
            a2[0] = *(const bf16x8*)(etp + SWZ(m * 128 + 16 * g, m));
            a2[1] = *(const bf16x8*)(etp + SWZ(m * 128 + 16 * g + 64, m));
        }
#pragma unroll
        for (int ci = 0; ci < 4; ++ci) {
            int c = ci * 16 + l15;
            bf16x8 b0 = *(const bf16x8*)(vtp + SWZ(c * 128 + 16 * g, c));
            bf16x8 b1 = *(const bf16x8*)(vtp + SWZ(c * 128 + 16 * g + 64, c));
            acc[ci] = MFMA(a2[0], b0, acc[ci]);
            acc[ci] = MFMA(a2[1], b1, acc[ci]);
        }
        acc[4] = MFMA(a2[0], onef, acc[4]);
        acc[4] = MFMA(a2[1], onef, acc[4]);
    };

    float4 ka[4], kb2[4];
    float va[16], vb2[16];
    loadT(0, ka, va);
    for (int t = 0; t < KTILES; t += 2) {
        body(t, 0, ka, va, kb2, vb2);
        body(t + 1, 1, kb2, vb2, ka, va);
    }

    // store partials: D[m][c]: m = wid*16 + 4g + r, c = ci*16 + l15
    float* dst = partial + ((size_t)bh * NCHK + chunk) * (M_ * CPK_);
#pragma unroll
    for (int ci = 0; ci < 5; ++ci)
#pragma unroll
        for (int r = 0; r < 4; ++r)
            dst[(wid * 16 + 4 * g + r) * CPK_ + ci * 16 + l15] = acc[ci][r];
}

// ---------------------------------------------------------------------------
// Reduce partials over chunks -> buf1[bh][m][CPK_]
// ---------------------------------------------------------------------------
__global__ void __launch_bounds__(256)
fa_r(const float* __restrict__ partial, float* __restrict__ buf1)
{
    int e = blockIdx.x * 256 + threadIdx.x;
    if (e >= BH_ * M_ * CPK_) return;
    int bh = e / (M_ * CPK_);
    int r  = e - bh * (M_ * CPK_);
    const float* src = partial + (size_t)bh * NCHK * (M_ * CPK_) + r;
    float s0 = 0.f, s1 = 0.f, s2 = 0.f, s3 = 0.f;
#pragma unroll
    for (int ch = 0; ch < NCHK; ch += 4) {
        s0 += src[(size_t)(ch + 0) * (M_ * CPK_)];
        s1 += src[(size_t)(ch + 1) * (M_ * CPK_)];
        s2 += src[(size_t)(ch + 2) * (M_ * CPK_)];
        s3 += src[(size_t)(ch + 3) * (M_ * CPK_)];
    }
    buf1[e] = (s0 + s1) + (s2 + s3);
}

// ---------------------------------------------------------------------------
// Phase Q: P = mfma(Qscaled, projT); e = exp2(P - h);
// Out^T-tiles: D[c][qrow] = mfma(buf1T, E_T); den = row c=64; out = num/den.
// ---------------------------------------------------------------------------
__global__ void __launch_bounds__(256)
fa_q(const float* __restrict__ qs, const float* __restrict__ proj,
     const float* __restrict__ buf1, float* __restrict__ out)
{
    const int chunk = blockIdx.x;
    const int bh    = blockIdx.y;
    const int b = bh >> 3, h = bh & 7;
    const int tid = threadIdx.x, wid = tid >> 6, lane = tid & 63;
    const int l15 = lane & 15, g = lane >> 4;

    __shared__ __align__(16) char eLb[2][TILE * M_ * 2];   // [qrow][m] bf16, swz by qrow
    __shared__ __align__(16) char b1tb[CPK_ * M_ * 2];     // [c][m] bf16, swz by c

    const int rows = S_ / NCHQ;
    const int s0 = chunk * rows;
    const size_t rs = (size_t)H_ * D_;
    const float* qb = qs + ((size_t)b * S_ * H_ + h) * D_;

    // stage buf1^T into LDS (c rows 65..79 are zeros in buf1 already)
    const float* b1 = buf1 + (size_t)bh * (M_ * CPK_);
    for (int i = tid; i < M_ * CPK_; i += 256) {
        int m = i / CPK_, c = i - m * CPK_;
        *(unsigned short*)(b1tb + SWZ(c * 128 + 2 * m, c)) = f2bf(b1[i]);
    }

    bf16x8 pf[4][2];
#pragma unroll
    for (int mt = 0; mt < 4; ++mt)
#pragma unroll
        for (int kk = 0; kk < 2; ++kk) {
            const float* p = proj + (mt * 16 + l15) * D_ + kk * 32 + g * 8;
            float4 a = *(const float4*)p, c = *(const float4*)(p + 4);
            bf16x8 f;
            f[0] = (short)f2bf(a.x); f[1] = (short)f2bf(a.y);
            f[2] = (short)f2bf(a.z); f[3] = (short)f2bf(a.w);
            f[4] = (short)f2bf(c.x); f[5] = (short)f2bf(c.y);
            f[6] = (short)f2bf(c.z); f[7] = (short)f2bf(c.w);
            pf[mt][kk] = f;
        }
    __syncthreads();

    // buf1^T A-fragments, read once: A[c][m]: c = ci*16+l15, m = g*8+j (+32*kk)
    bf16x8 af3[5][2];
#pragma unroll
    for (int ci = 0; ci < 5; ++ci)
#pragma unroll
        for (int kk = 0; kk < 2; ++kk) {
            int c = ci * 16 + l15;
            af3[ci][kk] = *(const bf16x8*)(b1tb + SWZ(c * 128 + 16 * g + 64 * kk, c));
        }

    auto loadQ = [&](int t, float4* qp) {
        int sb = s0 + t * TILE;
        const float* qrow = qb + (size_t)(sb + wid * 16 + l15) * rs;
        qp[0] = *(const float4*)(qrow + g * 8);
        qp[1] = *(const float4*)(qrow + g * 8 + 4);
        qp[2] = *(const float4*)(qrow + 32 + g * 8);
        qp[3] = *(const float4*)(qrow + 32 + g * 8 + 4);
    };

    auto body = [&](int t, int p, const float4* qc, float4* qn) {
        if (t + 1 < QTILES) loadQ(t + 1, qn);

        float kx[16];
#pragma unroll
        for (int i = 0; i < 4; ++i) {
            kx[4 * i + 0] = qc[i].x * XS_; kx[4 * i + 1] = qc[i].y * XS_;
            kx[4 * i + 2] = qc[i].z * XS_; kx[4 * i + 3] = qc[i].w * XS_;
        }
        float sq = 0.f;
#pragma unroll
        for (int j = 0; j < 16; ++j) sq += kx[j] * kx[j];
        sq += __shfl_xor(sq, 16);
        sq += __shfl_xor(sq, 32);
        float hrow = sq * HS_ + 3.0f;

        bf16x8 a1[2];
#pragma unroll
        for (int j = 0; j < 8; ++j) {
            a1[0][j] = (short)f2bf(kx[j]);
            a1[1][j] = (short)f2bf(kx[8 + j]);
        }

        f32x4 pa[4];
#pragma unroll
        for (int mt = 0; mt < 4; ++mt) {
            pa[mt] = (f32x4){0.f, 0.f, 0.f, 0.f};
            pa[mt] = MFMA(a1[0], pf[mt][0], pa[mt]);
            pa[mt] = MFMA(a1[1], pf[mt][1], pa[mt]);
        }

        float hr[4];
#pragma unroll
        for (int r = 0; r < 4; ++r) hr[r] = __shfl(hrow, 4 * g + r);

        char* elp = eLb[p];
#pragma unroll
        for (int mt = 0; mt < 4; ++mt) {
            int m = mt * 16 + l15;
#pragma unroll
            for (int r = 0; r < 4; ++r) {
                float e = fexp2(pa[mt][r] - hr[r]);
                int qrow = wid * 16 + 4 * g + r;
                *(unsigned short*)(elp + SWZ(qrow * 128 + 2 * m, qrow)) = f2bf(e);
            }
        }
        __syncthreads();

        bf16x8 b3[2];
        {
            int qrow = wid * 16 + l15;
            b3[0] = *(const bf16x8*)(elp + SWZ(qrow * 128 + 16 * g, qrow));
            b3[1] = *(const bf16x8*)(elp + SWZ(qrow * 128 + 16 * g + 64, qrow));
        }
        f32x4 dt[5];
#pragma unroll
        for (int ci = 0; ci < 5; ++ci) {
            dt[ci] = (f32x4){0.f, 0.f, 0.f, 0.f};
            dt[ci] = MFMA(af3[ci][0], b3[0], dt[ci]);
            dt[ci] = MFMA(af3[ci][1], b3[1], dt[ci]);
        }

        float den = __shfl(dt[4][0], l15);      // lanes g==0 hold den[qrow=l15]
        float rd = 1.0f / fmaxf(den, EPS_);

        int sg = s0 + t * TILE + wid * 16 + l15;
        size_t base = (((size_t)b * S_ + sg) * H_ + h) * D_;
#pragma unroll
        for (int ci = 0; ci < 4; ++ci) {
            f32x4 o;
#pragma unroll
            for (int r = 0; r < 4; ++r) o[r] = dt[ci][r] * rd;
            *(f32x4*)(out + base + ci * 16 + 4 * g) = o;
        }
    };

    float4 qa[4], qb2[4];
    loadQ(0, qa);
    for (int t = 0; t < QTILES; t += 2) {
        body(t, 0, qa, qb2);
        body(t + 1, 1, qb2, qa);
    }
}

extern "C" void kernel_launch(void* const* d_in, const int* in_sizes, int n_in,
                              void* d_out, int out_size, void* d_ws, size_t ws_size,
                              hipStream_t stream)
{
    const float* qs   = (const float*)d_in[0];
    const float* ks   = (const float*)d_in[1];
    const float* vs   = (const float*)d_in[2];
    const float* proj = (const float*)d_in[3];
    float* out = (float*)d_out;

    float* partial = (float*)d_ws;                          // BH*NCHK*M*CPK
    float* buf1 = partial + (size_t)BH_ * NCHK * (M_ * CPK_);

    fa_k<<<dim3(NCHK, BH_), 256, 0, stream>>>(ks, vs, proj, partial);
    int nred = (BH_ * M_ * CPK_ + 255) / 256;
    fa_r<<<dim3(nred), 256, 0, stream>>>(partial, buf1);
    fa_q<<<dim3(NCHQ, BH_), 256, 0, stream>>>(qs, proj, buf1, out);
}